// Round 12
// baseline (450.933 us; speedup 1.0000x reference)
//
#include <hip/hip_runtime.h>
#include <hip/hip_bf16.h>
#include <hip/hip_fp16.h>

// GCN: 3x (h@W -> symmetric-norm edge aggregation -> +b -> relu),
// segment_max pool over sorted batch, 2-layer MLP head.
// R25: ROW-RANGE parity partition for layers 2/3. R24 proved L2
// residency is achievable (FETCH halved) and worth ~0.67x per-request
// cost, but its feature-plane split doubled requests (2x32B vs 1x64B
// per edge) -> net 1.33x. Now: partition EDGES by source row into
// csrA (row<N/2) | csrB, parity-routed blocks (bid&1 -> XCD parity)
// gather full 64B rows from only their 3.2MB half-table (L2-resident)
// at exactly 1 request/edge. Partials (no bias/relu) -> pA/pB; layer2
// combined inside k_matmul30, layer3 via k_combine_pool (LDS-reduced
// atomicMax, R22 pattern). k_bucket/k_fuse extended with A/B counts,
// dual scans, dual cursors. k_agg16 iterates both ranges (its table
// already fits L2). Base = R22 (383.4us best).

#define WG 256
#define CAP 9216      // bucket capacity: mean 8192, sigma ~90 -> +11 sigma
#define T_EDGES 16384 // edges per bucketing block

__global__ void k_init(int* bcur, float* pooled, int nb32, int pooledN) {
    int i = blockIdx.x * blockDim.x + threadIdx.x;
    if (i < nb32) bcur[i] = 0;            // covers bcur + bcurA
    if (i < pooledN) pooled[i] = 0.0f;
}

// Phase 1: tile-local counting scatter into 256-node buckets.
// Record packs low: (col&255) | (row<<8)   high: w bits.
// Also counts A-edges (row < NHALF) per bucket into bcurA.
__global__ __launch_bounds__(1024)
void k_bucket(const int* __restrict__ row, const int* __restrict__ col,
              const float* __restrict__ w,
              int* bcur, int* bcurA, int2* __restrict__ buck,
              int E, int NB, int NHALF) {
    __shared__ int hist[512];
    __shared__ int histA[512];
    __shared__ int base[512];
    int tid = threadIdx.x;
    for (int i = tid; i < NB; i += 1024) { hist[i] = 0; histA[i] = 0; }
    __syncthreads();
    int start = blockIdx.x * T_EDGES;
    int end = min(start + T_EDGES, E);
    for (int i = start + tid; i < end; i += 1024) {
        int b = col[i] >> 8;
        atomicAdd(&hist[b], 1);
        if (row[i] < NHALF) atomicAdd(&histA[b], 1);
    }
    __syncthreads();
    for (int i = tid; i < NB; i += 1024) {
        int h = hist[i];
        base[i] = (h > 0) ? atomicAdd(&bcur[i * 16], h) : 0;  // reserve run
        int hA = histA[i];
        if (hA > 0) atomicAdd(&bcurA[i * 16], hA);
        hist[i] = 0; histA[i] = 0;
    }
    __syncthreads();
    for (int i = start + tid; i < end; i += 1024) {
        int c = col[i];
        int b = c >> 8;
        int off = atomicAdd(&hist[b], 1);
        int pos = base[b] + off;
        if (pos < CAP) {
            int2 pk;
            pk.x = (c & 255) | (row[i] << 8);
            pk.y = __float_as_int(w[i]);
            buck[(size_t)b * CAP + pos] = pk;
        }
    }
}

// Fused phase 2: dual bucket-level scans (A counts, total counts) ->
// absolute bases for csrA region [0,sumA) and csrB region [sumA,sumT);
// pass 1: per-col A/B counts + weight sums; dual local prefixes ->
// ptrA/ptrB + cursors; pass 2: scatter records by row-half.
__global__ __launch_bounds__(1024)
void k_fuse(const int* __restrict__ bcur, const int* __restrict__ bcurA,
            const int2* __restrict__ buck,
            float* __restrict__ dis, int* __restrict__ ptrA, int* __restrict__ ptrB,
            int2* __restrict__ csr, int N, int NB, int NHALF) {
    __shared__ int lcA[256];
    __shared__ int lcB[256];
    __shared__ float lw[256];
    __shared__ int shA[256];
    __shared__ int shB[256];
    __shared__ int curA[256];
    __shared__ int curB[256];
    __shared__ int sb[512];
    int b = blockIdx.x;
    int tid = threadIdx.x;
    // ---- scan A counts ----
    if (tid < 512) sb[tid] = (tid < NB) ? min(bcurA[tid * 16], CAP) : 0;
    if (tid < 256) { lcA[tid] = 0; lcB[tid] = 0; lw[tid] = 0.0f; }
    __syncthreads();
    for (int off = 1; off < 512; off <<= 1) {
        int v = (tid < 512 && tid >= off) ? sb[tid - off] : 0;
        __syncthreads();
        if (tid < 512) sb[tid] += v;
        __syncthreads();
    }
    int mA = min(bcurA[b * 16], CAP);
    int bbaseA = sb[b] - mA;
    int sumA = sb[511];
    __syncthreads();
    // ---- scan total counts ----
    if (tid < 512) sb[tid] = (tid < NB) ? min(bcur[tid * 16], CAP) : 0;
    __syncthreads();
    for (int off = 1; off < 512; off <<= 1) {
        int v = (tid < 512 && tid >= off) ? sb[tid - off] : 0;
        __syncthreads();
        if (tid < 512) sb[tid] += v;
        __syncthreads();
    }
    int mT = min(bcur[b * 16], CAP);
    int bbaseT = sb[b] - mT;
    int sumT = sb[511];
    int bbaseB = sumA + (bbaseT - bbaseA);   // exclusive B prefix, absolute
    if (b == 0 && tid == 0) { ptrA[N] = sumA; ptrB[N] = sumT; }
    const int2* bp = buck + (size_t)b * CAP;
    for (int i = tid; i < mT; i += 1024) {
        int2 pk = bp[i];
        int lcol = pk.x & 255;
        int rw = (int)(((unsigned)pk.x) >> 8);
        if (rw < NHALF) atomicAdd(&lcA[lcol], 1); else atomicAdd(&lcB[lcol], 1);
        atomicAdd(&lw[lcol], __int_as_float(pk.y));
    }
    __syncthreads();
    int lcntA = 0, lcntB = 0;
    if (tid < 256) { lcntA = lcA[tid]; shA[tid] = lcntA; lcntB = lcB[tid]; shB[tid] = lcntB; }
    __syncthreads();
    for (int off = 1; off < 256; off <<= 1) {
        int tA = (tid >= off && tid < 256) ? shA[tid - off] : 0;
        int tB = (tid >= off && tid < 256) ? shB[tid - off] : 0;
        __syncthreads();
        if (tid < 256) { shA[tid] += tA; shB[tid] += tB; }
        __syncthreads();
    }
    int node = (b << 8) + tid;
    if (tid < 256) {
        int baseA = bbaseA + shA[tid] - lcntA;
        int baseB = bbaseB + shB[tid] - lcntB;
        curA[tid] = baseA;
        curB[tid] = baseB;
        if (node < N) {
            ptrA[node] = baseA;
            ptrB[node] = baseB;
            float d = 1.0f + lw[tid];   // self-loop weight 1
            dis[node] = (d > 0.0f) ? (1.0f / sqrtf(d)) : 0.0f;
        }
    }
    __syncthreads();
    for (int i = tid; i < mT; i += 1024) {
        int2 pk = bp[i];
        int lcol = pk.x & 255;
        int rw = (int)(((unsigned)pk.x) >> 8);
        int pos = atomicAdd((rw < NHALF) ? &curA[lcol] : &curB[lcol], 1);
        int2 rec;
        rec.x = rw;
        rec.y = pk.y;                    // raw w (dis folded into features)
        csr[pos] = rec;
    }
}

// x' = dis[node] * x[node]  into N x 16 fp16 rows (cols 10-15 zero)
__global__ void k_stage(const float* __restrict__ x, const float* __restrict__ dis,
                        __half* __restrict__ xp, int n) {
    int gid = blockIdx.x * blockDim.x + threadIdx.x;
    int node = gid >> 4, f = gid & 15;
    if (node < n)
        xp[(size_t)node * 16 + f] = __float2half((f < 10) ? dis[node] * x[(size_t)node * 10 + f] : 0.0f);
}

// y[c] = dis[c] * ( sum_e w_e * x'[row_e] + x'[c] )   (fp16 32B rows)
// 4 nodes per wave (R22 body); iterates BOTH csr ranges (A then B).
__global__ __launch_bounds__(256, 4)
void k_agg16(const __half* __restrict__ xp, const float* __restrict__ dis,
             const int* __restrict__ ptrA, const int* __restrict__ ptrB,
             const int2* __restrict__ csr,
             float* __restrict__ y, int n) {
    int wid = (blockIdx.x * blockDim.x + threadIdx.x) >> 6;
    int lane = threadIdx.x & 63;
    int f = lane & 15;
    int laneq = lane & 48;
    int node = 4 * wid + (lane >> 4);
    bool valid = node < n;
    float a0 = 0.0f, a1 = 0.0f, a2 = 0.0f, a3 = 0.0f;
    for (int pass = 0; pass < 2; ++pass) {
        const int* P = pass ? ptrB : ptrA;
        int s = 0, e = 0;
        if (valid) { s = P[node]; e = P[node + 1]; }
        int len = e - s;
        int m01 = max(__shfl(len, 0, 64), __shfl(len, 16, 64));
        int m23 = max(__shfl(len, 32, 64), __shfl(len, 48, 64));
        int maxlen = max(m01, m23);
        for (int off = 0; off < maxlen; off += 16) {
            int idxv = 0; float nrmv = 0.0f;
            if (off + f < len) {
                int2 v = csr[s + off + f];
                idxv = v.x;
                nrmv = __int_as_float(v.y);
            }
            float wt[16], vt[16];
#pragma unroll
            for (int j = 0; j < 16; j++) {
                int r = __shfl(idxv, laneq | j, 64);
                wt[j] = __shfl(nrmv, laneq | j, 64);
                vt[j] = __half2float(xp[(size_t)r * 16 + f]);
            }
#pragma unroll
            for (int j = 0; j < 16; j += 4) {
                a0 = fmaf(wt[j],     vt[j],     a0);
                a1 = fmaf(wt[j + 1], vt[j + 1], a1);
                a2 = fmaf(wt[j + 2], vt[j + 2], a2);
                a3 = fmaf(wt[j + 3], vt[j + 3], a3);
            }
        }
    }
    if (valid) {
        float acc = (a0 + a1) + (a2 + a3);
        float r = dis[node] * (acc + __half2float(xp[(size_t)node * 16 + f]));
        y[(size_t)node * 16 + f] = r;   // cols 10-15 compute to 0
    }
}

// hw2 = dis * ( relu(y @ W1 + b1) @ W2 )  -- 8 nodes/block, LDS staged.
// Output fp16 full rows (stride 32 halves = 64B).
__global__ __launch_bounds__(256)
void k_lin1(const float* __restrict__ y, const float* __restrict__ W1,
            const float* __restrict__ b1, const float* __restrict__ W2,
            const float* __restrict__ dis, __half* __restrict__ out, int n) {
    __shared__ float W1s[10 * 32];
    __shared__ float W2s[30 * 32];
    __shared__ float b1s[32];
    __shared__ float ys[8][16];
    __shared__ float hs[8][32];
    int tid = threadIdx.x;
    for (int i = tid; i < 10 * 32; i += 256) { int k = i >> 5, f = i & 31; W1s[i] = (f < 30) ? W1[k * 30 + f] : 0.0f; }
    for (int i = tid; i < 30 * 32; i += 256) { int k = i >> 5, f = i & 31; W2s[i] = (f < 30) ? W2[k * 30 + f] : 0.0f; }
    if (tid < 32) b1s[tid] = (tid < 30) ? b1[tid] : 0.0f;
    int n8 = tid >> 5, f = tid & 31;
    int node = blockIdx.x * 8 + n8;
    __syncthreads();
    if (node < n && f < 16) ys[n8][f] = y[(size_t)node * 16 + f];
    __syncthreads();
    if (node < n) {
        float h = b1s[f];
#pragma unroll
        for (int k = 0; k < 10; k++) h += ys[n8][k] * W1s[k * 32 + f];
        h = fmaxf(h, 0.0f);
        if (f >= 30) h = 0.0f;
        hs[n8][f] = h;
    }
    __syncthreads();
    if (node < n) {
        float o = 0.0f;
#pragma unroll
        for (int k = 0; k < 30; k++) o += hs[n8][k] * W2s[k * 32 + f];
        out[(size_t)node * 32 + f] = __float2half(o * dis[node]);  // cols>=30 are 0
    }
}

// Partial aggregation (layers 2/3): parity-routed. Block -> (chunk of 4
// nodes, half) with half = bid&1 (XCD parity, proven by R24's FETCH
// halving). half==0 gathers only rows < NHALF (3.2MB L2-resident),
// half==1 the rest. Writes fp32 partial dis*(sum [+ self if row-half
// matches]) -- NO bias/relu (applied at combine).
__global__ __launch_bounds__(256, 4)
void k_agg_part(const __half* __restrict__ hw, const float* __restrict__ dis,
                const int* __restrict__ ptrA, const int* __restrict__ ptrB,
                const int2* __restrict__ csr,
                float* __restrict__ pA, float* __restrict__ pB,
                int n, int C, int NHALF) {
    int bid = blockIdx.x;
    int half = bid & 1;                       // XCD parity
    int chunk = (bid >> 3) * 4 + ((bid & 7) >> 1);
    if (chunk >= C) return;
    int node = chunk * 4 + (threadIdx.x >> 6);
    if (node >= n) return;
    int lane = threadIdx.x & 63;
    int f = lane & 31;
    int hlane = lane >> 5;
    const int* P = half ? ptrB : ptrA;
    int s = P[node];
    int e = P[node + 1];
    float a0 = 0.0f, a1 = 0.0f, a2 = 0.0f, a3 = 0.0f;
    for (int base = s; base < e; base += 32) {
        int idxv = 0; float nrmv = 0.0f;
        int src = base + lane;
        if (lane < 32 && src < e) {
            int2 v = csr[src];
            idxv = v.x;
            nrmv = __int_as_float(v.y);
        }
        float wt[16], vt[16];
#pragma unroll
        for (int j = 0; j < 16; j++) {
            int sl = 2 * j + hlane;              // halves take even/odd edges
            int r = __shfl(idxv, sl, 64);
            wt[j] = __shfl(nrmv, sl, 64);
            vt[j] = __half2float(hw[(size_t)r * 32 + f]);
        }
#pragma unroll
        for (int j = 0; j < 16; j += 4) {
            a0 = fmaf(wt[j],     vt[j],     a0);
            a1 = fmaf(wt[j + 1], vt[j + 1], a1);
            a2 = fmaf(wt[j + 2], vt[j + 2], a2);
            a3 = fmaf(wt[j + 3], vt[j + 3], a3);
        }
    }
    float acc = (a0 + a1) + (a2 + a3);
    acc += __shfl_xor(acc, 32, 64);
    // self term belongs to the parity matching the node's own row-half
    bool selfHere = (node < NHALF) == (half == 0);
    if (hlane == 0 && f < 30) {
        float selfv = selfHere ? __half2float(hw[(size_t)node * 32 + f]) : 0.0f;
        float r = dis[node] * (acc + selfv);
        float* out = half ? pB : pA;
        out[(size_t)node * 32 + f] = r;
    }
}

// hw' = dis[node] * ( relu(p0 + p1 + b2) @ W ), W 30x30 row-major.
// Combines the layer-2 partials inline. Out fp16 full rows, zero pad.
__global__ void k_matmul30(const float* __restrict__ in0, const float* __restrict__ in1,
                           const float* __restrict__ bias,
                           const float* __restrict__ W, const float* __restrict__ dis,
                           __half* __restrict__ out, int n) {
    __shared__ float Ws[30 * 30];
    __shared__ float bs[32];
    for (int idx = threadIdx.x; idx < 30 * 30; idx += blockDim.x) Ws[idx] = W[idx];
    if (threadIdx.x < 32) bs[threadIdx.x] = (threadIdx.x < 30) ? bias[threadIdx.x] : 0.0f;
    __syncthreads();
    int gid = blockIdx.x * blockDim.x + threadIdx.x;
    int node = gid >> 5;
    int f = gid & 31;
    if (node < n) {
        float acc = 0.0f;
        if (f < 30) {
            const float* p0 = in0 + (size_t)node * 32;
            const float* p1 = in1 + (size_t)node * 32;
#pragma unroll
            for (int k = 0; k < 30; k++) {
                float h = fmaxf(p0[k] + p1[k] + bs[k], 0.0f);
                acc += h * Ws[k * 30 + f];
            }
            acc *= dis[node];
        }
        out[(size_t)node * 32 + f] = __float2half(acc);   // coalesced, zero pad
    }
}

// Combine layer-3 partials + relu + segment_max pool. 8 nodes/block;
// LDS-reduce, single atomicMax set when the 8 nodes share a group.
__global__ __launch_bounds__(256)
void k_combine_pool(const float* __restrict__ pA, const float* __restrict__ pB,
                    const float* __restrict__ bias, const int* __restrict__ batch,
                    float* __restrict__ pooled, int n) {
    __shared__ float red[8][32];
    __shared__ int grp[8];
    int tid = threadIdx.x;
    int n8 = tid >> 5, f = tid & 31;
    int node = blockIdx.x * 8 + n8;
    float v = 0.0f;
    bool valid = (node < n) && (f < 30);
    if (valid)
        v = fmaxf(pA[(size_t)node * 32 + f] + pB[(size_t)node * 32 + f] + bias[f], 0.0f);
    red[n8][f] = v;
    if (f == 0) grp[n8] = (node < n) ? batch[node] : -1;
    __syncthreads();
    if (tid < 32 && tid < 30) {
        int g0 = grp[0];
        bool same = (g0 >= 0);
        for (int k = 1; k < 8; k++) same = same && (grp[k] == g0);
        if (same) {
            float m = red[0][tid];
#pragma unroll
            for (int k = 1; k < 8; k++) m = fmaxf(m, red[k][tid]);
            atomicMax((int*)&pooled[g0 * 32 + tid], __float_as_int(m));
        } else {
            for (int k = 0; k < 8; k++) {
                int g = grp[k];
                if (g >= 0)
                    atomicMax((int*)&pooled[g * 32 + tid], __float_as_int(red[k][tid]));
            }
        }
    }
}

__global__ void k_mlp(const float* __restrict__ pooled,
                      const float* __restrict__ LW1, const float* __restrict__ Lb1,
                      const float* __restrict__ LW2, const float* __restrict__ Lb2,
                      float* __restrict__ out, int G) {
    int g = blockIdx.x * blockDim.x + threadIdx.x;
    if (g >= G) return;
    float p[30];
#pragma unroll
    for (int k = 0; k < 30; k++) p[k] = pooled[g * 32 + k];
    float o0 = Lb2[0], o1 = Lb2[1];
#pragma unroll
    for (int j = 0; j < 10; j++) {
        float hj = Lb1[j];
#pragma unroll
        for (int k = 0; k < 30; k++) hj += p[k] * LW1[k * 10 + j];
        hj = fmaxf(hj, 0.0f);
        o0 += hj * LW2[j * 2 + 0];
        o1 += hj * LW2[j * 2 + 1];
    }
    out[g * 2 + 0] = o0;
    out[g * 2 + 1] = o1;
}

extern "C" void kernel_launch(void* const* d_in, const int* in_sizes, int n_in,
                              void* d_out, int out_size, void* d_ws, size_t ws_size,
                              hipStream_t stream) {
    const float* x     = (const float*)d_in[0];
    const int*   ei    = (const int*)d_in[1];
    const int*   batch = (const int*)d_in[2];
    const float* ew    = (const float*)d_in[3];
    const float* W1 = (const float*)d_in[4];  const float* b1  = (const float*)d_in[5];
    const float* W2 = (const float*)d_in[6];  const float* b2  = (const float*)d_in[7];
    const float* W3 = (const float*)d_in[8];  const float* b3  = (const float*)d_in[9];
    const float* LW1 = (const float*)d_in[10]; const float* Lb1 = (const float*)d_in[11];
    const float* LW2 = (const float*)d_in[12]; const float* Lb2 = (const float*)d_in[13];
    float* out = (float*)d_out;

    const int N = in_sizes[2];       // batch has N entries
    const int E = in_sizes[3];       // edge_weights has E entries
    const int G = out_size / 2;
    const int NHALF = N >> 1;
    const int* row = ei;
    const int* col = ei + E;

    const int NB = (N + 255) >> 8;   // 391 buckets (must be <= 512)

    char* p = (char*)d_ws;
    auto carve = [&](size_t bytes) -> void* {
        void* r = (void*)p;
        p += (bytes + 255) & ~(size_t)255;
        return r;
    };
    int*   ptrA      = (int*)carve((size_t)(N + 1) * 4);
    int*   ptrB      = (int*)carve((size_t)(N + 1) * 4);
    float* dis       = (float*)carve((size_t)N * 4);
    int*   bcur      = (int*)carve((size_t)NB * 16 * 4 * 2);   // bcur | bcurA
    int*   bcurA     = bcur + (size_t)NB * 16;
    int2*  csr       = (int2*)carve((size_t)E * 8);            // [A region | B region]
    // regionA: bucket storage (build) aliased with feature buffers:
    // layers need pA(N*32*4) | pB(N*32*4) | bufB fp16(N*32*2) = 32MB.
    // xp (fp16 N*16*2) at pA+0 and y16 (fp32 N*16*4) at pA+N*16*2 both
    // die before layer-2 k_agg_part writes pA.
    size_t buckBytes = (size_t)NB * CAP * 8;
    size_t featBytes = (size_t)N * 32 * 4 * 2 + (size_t)N * 32 * 2;
    char*  regionA   = (char*)carve(buckBytes > featBytes ? buckBytes : featBytes);
    int2*  buck      = (int2*)regionA;
    float* pA        = (float*)regionA;
    float* pB        = (float*)(regionA + (size_t)N * 32 * 4);
    __half* bufB     = (__half*)(regionA + (size_t)N * 32 * 4 * 2);  // fp16 full rows
    __half* xp       = (__half*)regionA;                             // N*16 fp16
    float* y16       = (float*)(regionA + (size_t)N * 16 * 2);       // N*16 fp32
    float* pooled    = (float*)carve((size_t)G * 32 * 4);

    int initN = (NB * 32 > G * 32) ? NB * 32 : G * 32;

    // --- build split CSR ---
    k_init<<<(initN + WG - 1) / WG, WG, 0, stream>>>(bcur, pooled, NB * 32, G * 32);
    k_bucket<<<(E + T_EDGES - 1) / T_EDGES, 1024, 0, stream>>>(row, col, ew, bcur, bcurA, buck, E, NB, NHALF);
    k_fuse<<<NB, 1024, 0, stream>>>(bcur, bcurA, buck, dis, ptrA, ptrB, csr, N, NB, NHALF);

    int agg16_grid = (int)(((size_t)((N + 3) / 4) * 64 + WG - 1) / WG);  // 4 nodes/wave
    int mm_grid    = (int)(((size_t)N * 32 + WG - 1) / WG);
    const int C    = (N + 3) / 4;                 // 4-node chunks
    int aggp_grid  = ((C + 3) / 4) * 8;           // (chunk,half), XCD-parity routed

    // layer 1 in 10-dim space: y = dc*(sum w*x'_r + x'_c), then lin1
    k_stage<<<(int)(((size_t)N * 16 + WG - 1) / WG), WG, 0, stream>>>(x, dis, xp, N);
    k_agg16<<<agg16_grid, WG, 0, stream>>>(xp, dis, ptrA, ptrB, csr, y16, N);
    k_lin1<<<(N + 7) / 8, 256, 0, stream>>>(y16, W1, b1, W2, dis, bufB, N);   // bufB = hw2 (fp16)
    // layer 2: parity partials -> combine inside matmul30
    k_agg_part<<<aggp_grid, WG, 0, stream>>>(bufB, dis, ptrA, ptrB, csr, pA, pB, N, C, NHALF);
    k_matmul30<<<mm_grid, WG, 0, stream>>>(pA, pB, b2, W3, dis, bufB, N);     // bufB = hw3 (fp16)
    // layer 3: parity partials -> combine + relu + segment_max pool
    k_agg_part<<<aggp_grid, WG, 0, stream>>>(bufB, dis, ptrA, ptrB, csr, pA, pB, N, C, NHALF);
    k_combine_pool<<<(N + 7) / 8, 256, 0, stream>>>(pA, pB, b3, batch, pooled, N);

    // head
    k_mlp<<<(G + WG - 1) / WG, WG, 0, stream>>>(pooled, LW1, Lb1, LW2, Lb2, out, G);
}

// Round 13
// 380.299 us; speedup vs baseline: 1.1857x; 1.1857x over previous
//
#include <hip/hip_runtime.h>
#include <hip/hip_bf16.h>
#include <hip/hip_fp16.h>

// GCN: 3x (h@W -> symmetric-norm edge aggregation -> +b -> relu),
// segment_max pool over sorted batch, 2-layer MLP head.
// R26: revert to R22 (383.4us best). R24/R25 proved the agg family is
// at its structural floor: L2-residency schemes (feature planes,
// row-range partition) pay more in request-count/run-length than the
// ~0.67x latency win returns; R22's 1x64B-request-per-edge full-run
// form is the empirical optimum (9 variants bracket it). This round:
// (1) h2 stored fp16 (halves k_matmul30 input traffic), (2) vectorized
// int4/float4 edge reads in k_bucket (4x fewer load instrs).

#define WG 256
#define CAP 9216      // bucket capacity: mean 8192, sigma ~90 -> +11 sigma
#define T_EDGES 16384 // edges per bucketing block

__global__ void k_init(int* bcur, float* pooled, int nb16, int pooledN) {
    int i = blockIdx.x * blockDim.x + threadIdx.x;
    if (i < nb16) bcur[i] = 0;
    if (i < pooledN) pooled[i] = 0.0f;
}

// Phase 1: tile-local counting scatter into 256-node buckets.
// Record packs low: (col&255) | (row<<8)   high: w bits.
// Vectorized int4/float4 edge reads (4 edges per thread per iter).
__global__ __launch_bounds__(1024)
void k_bucket(const int* __restrict__ row, const int* __restrict__ col,
              const float* __restrict__ w,
              int* bcur, int2* __restrict__ buck, int E, int NB) {
    __shared__ int hist[512];
    __shared__ int base[512];
    int tid = threadIdx.x;
    for (int i = tid; i < NB; i += 1024) hist[i] = 0;
    __syncthreads();
    int start = blockIdx.x * T_EDGES;
    int end = min(start + T_EDGES, E);
    int nvec = (end - start) >> 2;               // int4 groups in tile
    const int4* col4 = reinterpret_cast<const int4*>(col + start);
    for (int v = tid; v < nvec; v += 1024) {
        int4 c = col4[v];
        atomicAdd(&hist[c.x >> 8], 1);
        atomicAdd(&hist[c.y >> 8], 1);
        atomicAdd(&hist[c.z >> 8], 1);
        atomicAdd(&hist[c.w >> 8], 1);
    }
    for (int i = start + (nvec << 2) + tid; i < end; i += 1024)   // tail
        atomicAdd(&hist[col[i] >> 8], 1);
    __syncthreads();
    for (int i = tid; i < NB; i += 1024) {
        int h = hist[i];
        base[i] = (h > 0) ? atomicAdd(&bcur[i * 16], h) : 0;  // reserve run
        hist[i] = 0;
    }
    __syncthreads();
    const int4* row4 = reinterpret_cast<const int4*>(row + start);
    const float4* w4 = reinterpret_cast<const float4*>(w + start);
    for (int v = tid; v < nvec; v += 1024) {
        int4 c = col4[v];
        int4 r = row4[v];
        float4 ww = w4[v];
        int cc[4] = { c.x, c.y, c.z, c.w };
        int rr[4] = { r.x, r.y, r.z, r.w };
        float wv[4] = { ww.x, ww.y, ww.z, ww.w };
#pragma unroll
        for (int k = 0; k < 4; k++) {
            int b = cc[k] >> 8;
            int off = atomicAdd(&hist[b], 1);
            int pos = base[b] + off;
            if (pos < CAP) {
                int2 pk;
                pk.x = (cc[k] & 255) | (rr[k] << 8);
                pk.y = __float_as_int(wv[k]);
                buck[(size_t)b * CAP + pos] = pk;
            }
        }
    }
    for (int i = start + (nvec << 2) + tid; i < end; i += 1024) {  // tail
        int c = col[i];
        int b = c >> 8;
        int off = atomicAdd(&hist[b], 1);
        int pos = base[b] + off;
        if (pos < CAP) {
            int2 pk;
            pk.x = (c & 255) | (row[i] << 8);
            pk.y = __float_as_int(w[i]);
            buck[(size_t)b * CAP + pos] = pk;
        }
    }
}

// Fused phase 2 (incl. bucket-level scan): per bucket --
// scan bcur in LDS -> bbase; pass 1: LDS count+wsum over records; write
// dis; in-bucket prefix -> ptr + cursors; pass 2 (L2-hot re-read):
// scatter records to final CSR as (row, raw w).
__global__ __launch_bounds__(1024)
void k_fuse(const int* __restrict__ bcur, const int2* __restrict__ buck,
            float* __restrict__ dis, int* __restrict__ ptr,
            int2* __restrict__ csr, int N, int NB) {
    __shared__ int lc[256];
    __shared__ float lw[256];
    __shared__ int sh[256];
    __shared__ int cur[256];
    __shared__ int sb[512];
    int b = blockIdx.x;
    int tid = threadIdx.x;
    if (tid < 512) sb[tid] = (tid < NB) ? min(bcur[tid * 16], CAP) : 0;
    if (tid < 256) { lc[tid] = 0; lw[tid] = 0.0f; }
    __syncthreads();
    for (int off = 1; off < 512; off <<= 1) {
        int v = (tid < 512 && tid >= off) ? sb[tid - off] : 0;
        __syncthreads();
        if (tid < 512) sb[tid] += v;
        __syncthreads();
    }
    int m = min(bcur[b * 16], CAP);
    int bbase = sb[b] - m;               // exclusive prefix for this bucket
    if (b == 0 && tid == 0) ptr[N] = sb[511];  // grand total
    const int2* bp = buck + (size_t)b * CAP;
    for (int i = tid; i < m; i += 1024) {
        int2 pk = bp[i];
        int lcol = pk.x & 255;
        atomicAdd(&lc[lcol], 1);
        atomicAdd(&lw[lcol], __int_as_float(pk.y));
    }
    __syncthreads();
    int lcnt = 0;
    if (tid < 256) { lcnt = lc[tid]; sh[tid] = lcnt; }
    __syncthreads();
    for (int off = 1; off < 256; off <<= 1) {
        int t = (tid >= off && tid < 256) ? sh[tid - off] : 0;
        __syncthreads();
        if (tid < 256) sh[tid] += t;
        __syncthreads();
    }
    int node = (b << 8) + tid;
    if (tid < 256) {
        int base = bbase + sh[tid] - lcnt;  // exclusive node prefix
        cur[tid] = base;
        if (node < N) {
            ptr[node] = base;
            float d = 1.0f + lw[tid];   // self-loop weight 1
            dis[node] = (d > 0.0f) ? (1.0f / sqrtf(d)) : 0.0f;
        }
    }
    __syncthreads();
    for (int i = tid; i < m; i += 1024) {
        int2 pk = bp[i];
        int lcol = pk.x & 255;
        int pos = atomicAdd(&cur[lcol], 1);
        int2 rec;
        rec.x = (int)(((unsigned)pk.x) >> 8);
        rec.y = pk.y;                    // raw w (dis folded into features)
        csr[pos] = rec;
    }
}

// x' = dis[node] * x[node]  into N x 16 fp16 rows (cols 10-15 zero)
__global__ void k_stage(const float* __restrict__ x, const float* __restrict__ dis,
                        __half* __restrict__ xp, int n) {
    int gid = blockIdx.x * blockDim.x + threadIdx.x;
    int node = gid >> 4, f = gid & 15;
    if (node < n)
        xp[(size_t)node * 16 + f] = __float2half((f < 10) ? dis[node] * x[(size_t)node * 10 + f] : 0.0f);
}

// y[c] = dis[c] * ( sum_e w_e * x'[row_e] + x'[c] )   (fp16 32B rows)
// 4 nodes per wave: quarter q owns node 4*wid+q, f = lane&15. Each
// quarter loads its own 16-record CSR chunk; shfl src (lane&48)|j.
// One gather instr = 4 distinct 32B segments. Output y fp32. (R22 body)
__global__ __launch_bounds__(256, 4)
void k_agg16(const __half* __restrict__ xp, const float* __restrict__ dis,
             const int* __restrict__ ptr, const int2* __restrict__ csr,
             float* __restrict__ y, int n) {
    int wid = (blockIdx.x * blockDim.x + threadIdx.x) >> 6;
    int lane = threadIdx.x & 63;
    int f = lane & 15;
    int laneq = lane & 48;
    int node = 4 * wid + (lane >> 4);
    bool valid = node < n;
    int s = 0, e = 0;
    if (valid) { s = ptr[node]; e = ptr[node + 1]; }
    int len = e - s;
    int m01 = max(__shfl(len, 0, 64), __shfl(len, 16, 64));
    int m23 = max(__shfl(len, 32, 64), __shfl(len, 48, 64));
    int maxlen = max(m01, m23);
    float a0 = 0.0f, a1 = 0.0f, a2 = 0.0f, a3 = 0.0f;
    for (int off = 0; off < maxlen; off += 16) {
        int idxv = 0; float nrmv = 0.0f;
        if (off + f < len) {
            int2 v = csr[s + off + f];
            idxv = v.x;
            nrmv = __int_as_float(v.y);
        }
        float wt[16], vt[16];
#pragma unroll
        for (int j = 0; j < 16; j++) {
            int r = __shfl(idxv, laneq | j, 64);
            wt[j] = __shfl(nrmv, laneq | j, 64);
            vt[j] = __half2float(xp[(size_t)r * 16 + f]);
        }
#pragma unroll
        for (int j = 0; j < 16; j += 4) {
            a0 = fmaf(wt[j],     vt[j],     a0);
            a1 = fmaf(wt[j + 1], vt[j + 1], a1);
            a2 = fmaf(wt[j + 2], vt[j + 2], a2);
            a3 = fmaf(wt[j + 3], vt[j + 3], a3);
        }
    }
    if (valid) {
        float acc = (a0 + a1) + (a2 + a3);
        float r = dis[node] * (acc + __half2float(xp[(size_t)node * 16 + f]));
        y[(size_t)node * 16 + f] = r;   // cols 10-15 compute to 0
    }
}

// hw2 = dis * ( relu(y @ W1 + b1) @ W2 )  -- 8 nodes/block, LDS staged.
// Output fp16 rows (stride 32 halves = 64B).
__global__ __launch_bounds__(256)
void k_lin1(const float* __restrict__ y, const float* __restrict__ W1,
            const float* __restrict__ b1, const float* __restrict__ W2,
            const float* __restrict__ dis, __half* __restrict__ out, int n) {
    __shared__ float W1s[10 * 32];
    __shared__ float W2s[30 * 32];
    __shared__ float b1s[32];
    __shared__ float ys[8][16];
    __shared__ float hs[8][32];
    int tid = threadIdx.x;
    for (int i = tid; i < 10 * 32; i += 256) { int k = i >> 5, f = i & 31; W1s[i] = (f < 30) ? W1[k * 30 + f] : 0.0f; }
    for (int i = tid; i < 30 * 32; i += 256) { int k = i >> 5, f = i & 31; W2s[i] = (f < 30) ? W2[k * 30 + f] : 0.0f; }
    if (tid < 32) b1s[tid] = (tid < 30) ? b1[tid] : 0.0f;
    int n8 = tid >> 5, f = tid & 31;
    int node = blockIdx.x * 8 + n8;
    __syncthreads();
    if (node < n && f < 16) ys[n8][f] = y[(size_t)node * 16 + f];
    __syncthreads();
    if (node < n) {
        float h = b1s[f];
#pragma unroll
        for (int k = 0; k < 10; k++) h += ys[n8][k] * W1s[k * 32 + f];
        h = fmaxf(h, 0.0f);
        if (f >= 30) h = 0.0f;
        hs[n8][f] = h;
    }
    __syncthreads();
    if (node < n) {
        float o = 0.0f;
#pragma unroll
        for (int k = 0; k < 30; k++) o += hs[n8][k] * W2s[k * 32 + f];
        out[(size_t)node * 32 + f] = __float2half(o * dis[node]);  // cols>=30 are 0
    }
}

// hw' = dis[node] * (in @ W)   (W is 30 x 30 row-major), in fp16 rows
// (h2 stored fp16 -- R26), out fp16 rows stride 32 (cols 30,31 zeroed).
__global__ void k_matmul30(const __half* __restrict__ in,
                           const float* __restrict__ W, const float* __restrict__ dis,
                           __half* __restrict__ out, int n) {
    __shared__ float Ws[30 * 30];
    for (int idx = threadIdx.x; idx < 30 * 30; idx += blockDim.x) Ws[idx] = W[idx];
    __syncthreads();
    int gid = blockIdx.x * blockDim.x + threadIdx.x;
    int node = gid >> 5;
    int f = gid & 31;
    if (node < n) {
        float acc = 0.0f;
        if (f < 30) {
            const __half* ip = in + (size_t)node * 32;
#pragma unroll
            for (int k = 0; k < 30; k++) acc += __half2float(ip[k]) * Ws[k * 30 + f];
            acc *= dis[node];
        }
        out[(size_t)node * 32 + f] = __float2half(acc);   // coalesced, zero pad
    }
}

// h = relu( dis[c] * ( sum_e w_e*hw'[row_e] + hw'[c] ) + b )  -> fp16
// One wave per node; halves process even/odd edges -> 2 distinct 64B
// segments per gather instr (fp16 rows). R22 body, fp16 store epilogue.
__global__ __launch_bounds__(256, 4)
void k_agg_store(const __half* __restrict__ hw, const float* __restrict__ dis,
                 const int* __restrict__ ptr, const int2* __restrict__ csr,
                 const float* __restrict__ bias,
                 __half* __restrict__ out, int n) {
    int wid = (blockIdx.x * blockDim.x + threadIdx.x) >> 6;
    int lane = threadIdx.x & 63;
    if (wid >= n) return;
    int f = lane & 31;
    int half = lane >> 5;
    int s = ptr[wid];
    int e = ptr[wid + 1];
    float a0 = 0.0f, a1 = 0.0f, a2 = 0.0f, a3 = 0.0f;
    for (int base = s; base < e; base += 32) {
        int idxv = 0; float nrmv = 0.0f;
        int src = base + lane;
        if (lane < 32 && src < e) {
            int2 v = csr[src];
            idxv = v.x;
            nrmv = __int_as_float(v.y);
        }
        float wt[16], vt[16];
#pragma unroll
        for (int j = 0; j < 16; j++) {
            int sl = 2 * j + half;               // halves take even/odd edges
            int r = __shfl(idxv, sl, 64);
            wt[j] = __shfl(nrmv, sl, 64);
            vt[j] = __half2float(hw[(size_t)r * 32 + f]);
        }
#pragma unroll
        for (int j = 0; j < 16; j += 4) {
            a0 = fmaf(wt[j],     vt[j],     a0);
            a1 = fmaf(wt[j + 1], vt[j + 1], a1);
            a2 = fmaf(wt[j + 2], vt[j + 2], a2);
            a3 = fmaf(wt[j + 3], vt[j + 3], a3);
        }
    }
    float acc = (a0 + a1) + (a2 + a3);
    acc += __shfl_xor(acc, 32, 64);
    float dc = dis[wid];
    float r = dc * (acc + __half2float(hw[(size_t)wid * 32 + f]));
    if (half == 0) {
        float v = (f < 30) ? fmaxf(r + bias[f], 0.0f) : 0.0f;
        out[(size_t)wid * 32 + f] = __float2half(v);
    }
}

// Same loop, pool epilogue with LDS block pre-reduction (R22): one
// atomic set per block when the 4 consecutive nodes share a group.
__global__ __launch_bounds__(256, 4)
void k_agg_pool(const __half* __restrict__ hw, const float* __restrict__ dis,
                const int* __restrict__ ptr, const int2* __restrict__ csr,
                const float* __restrict__ bias, const int* __restrict__ batch,
                float* __restrict__ pooled, int n) {
    __shared__ float red[4][32];
    __shared__ int grp[4];
    int wid = (blockIdx.x * blockDim.x + threadIdx.x) >> 6;
    int lane = threadIdx.x & 63;
    int f = lane & 31;
    int half = lane >> 5;
    bool valid = wid < n;
    int s = 0, e = 0;
    if (valid) { s = ptr[wid]; e = ptr[wid + 1]; }
    float a0 = 0.0f, a1 = 0.0f, a2 = 0.0f, a3 = 0.0f;
    for (int base = s; base < e; base += 32) {
        int idxv = 0; float nrmv = 0.0f;
        int src = base + lane;
        if (lane < 32 && src < e) {
            int2 v = csr[src];
            idxv = v.x;
            nrmv = __int_as_float(v.y);
        }
        float wt[16], vt[16];
#pragma unroll
        for (int j = 0; j < 16; j++) {
            int sl = 2 * j + half;
            int r = __shfl(idxv, sl, 64);
            wt[j] = __shfl(nrmv, sl, 64);
            vt[j] = __half2float(hw[(size_t)r * 32 + f]);
        }
#pragma unroll
        for (int j = 0; j < 16; j += 4) {
            a0 = fmaf(wt[j],     vt[j],     a0);
            a1 = fmaf(wt[j + 1], vt[j + 1], a1);
            a2 = fmaf(wt[j + 2], vt[j + 2], a2);
            a3 = fmaf(wt[j + 3], vt[j + 3], a3);
        }
    }
    float acc = (a0 + a1) + (a2 + a3);
    acc += __shfl_xor(acc, 32, 64);
    float rv = 0.0f;
    if (valid && half == 0 && f < 30) {
        float dc = dis[wid];
        float r = dc * (acc + __half2float(hw[(size_t)wid * 32 + f]));
        rv = fmaxf(r + bias[f], 0.0f);
    }
    int w = threadIdx.x >> 6;                 // wave index in block (0..3)
    if (half == 0) red[w][f] = rv;            // f>=30 lanes write 0
    if (lane == 0) grp[w] = valid ? batch[wid] : -1;
    __syncthreads();
    if (w == 0 && half == 0 && f < 30) {
        int g0 = grp[0], g1 = grp[1], g2 = grp[2], g3 = grp[3];
        if (g0 >= 0 && g0 == g1 && g0 == g2 && g0 == g3) {
            float m = fmaxf(fmaxf(red[0][f], red[1][f]), fmaxf(red[2][f], red[3][f]));
            atomicMax((int*)&pooled[g0 * 32 + f], __float_as_int(m));
        } else {
            if (g0 >= 0) atomicMax((int*)&pooled[g0 * 32 + f], __float_as_int(red[0][f]));
            if (g1 >= 0) atomicMax((int*)&pooled[g1 * 32 + f], __float_as_int(red[1][f]));
            if (g2 >= 0) atomicMax((int*)&pooled[g2 * 32 + f], __float_as_int(red[2][f]));
            if (g3 >= 0) atomicMax((int*)&pooled[g3 * 32 + f], __float_as_int(red[3][f]));
        }
    }
}

__global__ void k_mlp(const float* __restrict__ pooled,
                      const float* __restrict__ LW1, const float* __restrict__ Lb1,
                      const float* __restrict__ LW2, const float* __restrict__ Lb2,
                      float* __restrict__ out, int G) {
    int g = blockIdx.x * blockDim.x + threadIdx.x;
    if (g >= G) return;
    float p[30];
#pragma unroll
    for (int k = 0; k < 30; k++) p[k] = pooled[g * 32 + k];
    float o0 = Lb2[0], o1 = Lb2[1];
#pragma unroll
    for (int j = 0; j < 10; j++) {
        float hj = Lb1[j];
#pragma unroll
        for (int k = 0; k < 30; k++) hj += p[k] * LW1[k * 10 + j];
        hj = fmaxf(hj, 0.0f);
        o0 += hj * LW2[j * 2 + 0];
        o1 += hj * LW2[j * 2 + 1];
    }
    out[g * 2 + 0] = o0;
    out[g * 2 + 1] = o1;
}

extern "C" void kernel_launch(void* const* d_in, const int* in_sizes, int n_in,
                              void* d_out, int out_size, void* d_ws, size_t ws_size,
                              hipStream_t stream) {
    const float* x     = (const float*)d_in[0];
    const int*   ei    = (const int*)d_in[1];
    const int*   batch = (const int*)d_in[2];
    const float* ew    = (const float*)d_in[3];
    const float* W1 = (const float*)d_in[4];  const float* b1  = (const float*)d_in[5];
    const float* W2 = (const float*)d_in[6];  const float* b2  = (const float*)d_in[7];
    const float* W3 = (const float*)d_in[8];  const float* b3  = (const float*)d_in[9];
    const float* LW1 = (const float*)d_in[10]; const float* Lb1 = (const float*)d_in[11];
    const float* LW2 = (const float*)d_in[12]; const float* Lb2 = (const float*)d_in[13];
    float* out = (float*)d_out;

    const int N = in_sizes[2];       // batch has N entries
    const int E = in_sizes[3];       // edge_weights has E entries
    const int G = out_size / 2;
    const int* row = ei;
    const int* col = ei + E;

    const int NB = (N + 255) >> 8;   // 391 buckets (must be <= 512)

    char* p = (char*)d_ws;
    auto carve = [&](size_t bytes) -> void* {
        void* r = (void*)p;
        p += (bytes + 255) & ~(size_t)255;
        return r;
    };
    int*   ptr       = (int*)carve((size_t)(N + 1) * 4);
    float* dis       = (float*)carve((size_t)N * 4);
    int*   bcur      = (int*)carve((size_t)NB * 16 * 4);
    int2*  csr       = (int2*)carve((size_t)E * 8);
    // regionA: bucket storage (build) aliased with feature buffers (layers).
    // Layer layout: [h2 fp16: N*32*2][...][bufB fp16: N*32*2 at N*32*4].
    // xp (fp16, N*16*2) at offset 0 and y16 (fp32, N*16*4) at offset
    // N*16*2 both alias h2's region; both dead before layer-2 writes.
    size_t buckBytes = (size_t)NB * CAP * 8;
    size_t featBytes = (size_t)N * 32 * 4 * 2;
    char*  regionA   = (char*)carve(buckBytes > featBytes ? buckBytes : featBytes);
    int2*  buck      = (int2*)regionA;
    __half* h2buf    = (__half*)regionA;                            // N*32 fp16
    __half* xp       = (__half*)regionA;                            // N*16 fp16
    float* y16       = (float*)(regionA + (size_t)N * 16 * 2);      // N*16 fp32
    __half* bufB     = (__half*)(regionA + (size_t)N * 32 * 4);     // N*32 fp16
    float* pooled    = (float*)carve((size_t)G * 32 * 4);

    int initN = (NB * 16 > G * 32) ? NB * 16 : G * 32;

    // --- build CSR ---
    k_init<<<(initN + WG - 1) / WG, WG, 0, stream>>>(bcur, pooled, NB * 16, G * 32);
    k_bucket<<<(E + T_EDGES - 1) / T_EDGES, 1024, 0, stream>>>(row, col, ew, bcur, buck, E, NB);
    k_fuse<<<NB, 1024, 0, stream>>>(bcur, buck, dis, ptr, csr, N, NB);

    int agg_grid   = (int)(((size_t)N * 64 + WG - 1) / WG);              // 1 node/wave
    int agg16_grid = (int)(((size_t)((N + 3) / 4) * 64 + WG - 1) / WG);  // 4 nodes/wave
    int mm_grid    = (int)(((size_t)N * 32 + WG - 1) / WG);

    // layer 1 in 10-dim space: y = dc*(sum w*x'_r + x'_c), then lin1
    k_stage<<<(int)(((size_t)N * 16 + WG - 1) / WG), WG, 0, stream>>>(x, dis, xp, N);
    k_agg16<<<agg16_grid, WG, 0, stream>>>(xp, dis, ptr, csr, y16, N);
    k_lin1<<<(N + 7) / 8, 256, 0, stream>>>(y16, W1, b1, W2, dis, bufB, N);   // bufB = hw2 (fp16)
    // layer 2
    k_agg_store<<<agg_grid, WG, 0, stream>>>(bufB, dis, ptr, csr, b2, h2buf, N); // h2 (fp16)
    k_matmul30<<<mm_grid, WG, 0, stream>>>(h2buf, W3, dis, bufB, N);          // bufB = hw3 (fp16)
    // layer 3 + fused segment-max pool (LDS pre-reduced atomics)
    k_agg_pool<<<agg_grid, WG, 0, stream>>>(bufB, dis, ptr, csr, b3, batch, pooled, N);

    // head
    k_mlp<<<(G + WG - 1) / WG, WG, 0, stream>>>(pooled, LW1, Lb1, LW2, Lb2, out, G);
}

// Round 14
// 369.429 us; speedup vs baseline: 1.2206x; 1.0294x over previous
//
#include <hip/hip_runtime.h>
#include <hip/hip_bf16.h>
#include <hip/hip_fp16.h>

// GCN: 3x (h@W -> symmetric-norm edge aggregation -> +b -> relu),
// segment_max pool over sorted batch, 2-layer MLP head.
// R27: build-phase + lin1 optimization (aggs untouched -- R22/R26 form
// is their measured floor, 9 variants bracket it).
// (1) k_fuse: pass-2 was 3.2M random 8B global writes (1 line/record).
//     Now: bucket-LOCAL cursors scatter records into a CAP-sized LDS
//     array (73.7KB -- free: 391-block grid caps occupancy at 2/CU
//     anyway), then a fully-coalesced linear LDS->csr copy. ~16x fewer
//     write transactions.
// (2) k_lin1: 32 nodes/block (4 iterations over staged weights) --
//     weight-staging L2 traffic 64MB -> 16MB.

#define WG 256
#define CAP 9216      // bucket capacity: mean 8192, sigma ~90 -> +11 sigma
#define T_EDGES 16384 // edges per bucketing block

__global__ void k_init(int* bcur, float* pooled, int nb16, int pooledN) {
    int i = blockIdx.x * blockDim.x + threadIdx.x;
    if (i < nb16) bcur[i] = 0;
    if (i < pooledN) pooled[i] = 0.0f;
}

// Phase 1: tile-local counting scatter into 256-node buckets.
// Record packs low: (col&255) | (row<<8)   high: w bits.
// Vectorized int4/float4 edge reads (4 edges per thread per iter).
__global__ __launch_bounds__(1024)
void k_bucket(const int* __restrict__ row, const int* __restrict__ col,
              const float* __restrict__ w,
              int* bcur, int2* __restrict__ buck, int E, int NB) {
    __shared__ int hist[512];
    __shared__ int base[512];
    int tid = threadIdx.x;
    for (int i = tid; i < NB; i += 1024) hist[i] = 0;
    __syncthreads();
    int start = blockIdx.x * T_EDGES;
    int end = min(start + T_EDGES, E);
    int nvec = (end - start) >> 2;               // int4 groups in tile
    const int4* col4 = reinterpret_cast<const int4*>(col + start);
    for (int v = tid; v < nvec; v += 1024) {
        int4 c = col4[v];
        atomicAdd(&hist[c.x >> 8], 1);
        atomicAdd(&hist[c.y >> 8], 1);
        atomicAdd(&hist[c.z >> 8], 1);
        atomicAdd(&hist[c.w >> 8], 1);
    }
    for (int i = start + (nvec << 2) + tid; i < end; i += 1024)   // tail
        atomicAdd(&hist[col[i] >> 8], 1);
    __syncthreads();
    for (int i = tid; i < NB; i += 1024) {
        int h = hist[i];
        base[i] = (h > 0) ? atomicAdd(&bcur[i * 16], h) : 0;  // reserve run
        hist[i] = 0;
    }
    __syncthreads();
    const int4* row4 = reinterpret_cast<const int4*>(row + start);
    const float4* w4 = reinterpret_cast<const float4*>(w + start);
    for (int v = tid; v < nvec; v += 1024) {
        int4 c = col4[v];
        int4 r = row4[v];
        float4 ww = w4[v];
        int cc[4] = { c.x, c.y, c.z, c.w };
        int rr[4] = { r.x, r.y, r.z, r.w };
        float wv[4] = { ww.x, ww.y, ww.z, ww.w };
#pragma unroll
        for (int k = 0; k < 4; k++) {
            int b = cc[k] >> 8;
            int off = atomicAdd(&hist[b], 1);
            int pos = base[b] + off;
            if (pos < CAP) {
                int2 pk;
                pk.x = (cc[k] & 255) | (rr[k] << 8);
                pk.y = __float_as_int(wv[k]);
                buck[(size_t)b * CAP + pos] = pk;
            }
        }
    }
    for (int i = start + (nvec << 2) + tid; i < end; i += 1024) {  // tail
        int c = col[i];
        int b = c >> 8;
        int off = atomicAdd(&hist[b], 1);
        int pos = base[b] + off;
        if (pos < CAP) {
            int2 pk;
            pk.x = (c & 255) | (row[i] << 8);
            pk.y = __float_as_int(w[i]);
            buck[(size_t)b * CAP + pos] = pk;
        }
    }
}

// Fused phase 2 (incl. bucket-level scan): per bucket --
// scan bcur in LDS -> bbase; pass 1: LDS count+wsum over records; write
// dis; in-bucket prefix -> LOCAL cursors; pass 2: scatter records into
// LDS csr image; coalesced linear write-out to global csr.
__global__ __launch_bounds__(1024)
void k_fuse(const int* __restrict__ bcur, const int2* __restrict__ buck,
            float* __restrict__ dis, int* __restrict__ ptr,
            int2* __restrict__ csr, int N, int NB) {
    __shared__ int lc[256];
    __shared__ float lw[256];
    __shared__ int sh[256];
    __shared__ int cur[256];
    __shared__ int sb[512];
    __shared__ int2 lcsr[CAP];               // 73.7KB LDS csr image
    int b = blockIdx.x;
    int tid = threadIdx.x;
    if (tid < 512) sb[tid] = (tid < NB) ? min(bcur[tid * 16], CAP) : 0;
    if (tid < 256) { lc[tid] = 0; lw[tid] = 0.0f; }
    __syncthreads();
    for (int off = 1; off < 512; off <<= 1) {
        int v = (tid < 512 && tid >= off) ? sb[tid - off] : 0;
        __syncthreads();
        if (tid < 512) sb[tid] += v;
        __syncthreads();
    }
    int m = min(bcur[b * 16], CAP);
    int bbase = sb[b] - m;               // exclusive prefix for this bucket
    if (b == 0 && tid == 0) ptr[N] = sb[511];  // grand total
    const int2* bp = buck + (size_t)b * CAP;
    for (int i = tid; i < m; i += 1024) {
        int2 pk = bp[i];
        int lcol = pk.x & 255;
        atomicAdd(&lc[lcol], 1);
        atomicAdd(&lw[lcol], __int_as_float(pk.y));
    }
    __syncthreads();
    int lcnt = 0;
    if (tid < 256) { lcnt = lc[tid]; sh[tid] = lcnt; }
    __syncthreads();
    for (int off = 1; off < 256; off <<= 1) {
        int t = (tid >= off && tid < 256) ? sh[tid - off] : 0;
        __syncthreads();
        if (tid < 256) sh[tid] += t;
        __syncthreads();
    }
    int node = (b << 8) + tid;
    if (tid < 256) {
        int lbase = sh[tid] - lcnt;          // LOCAL exclusive node prefix
        cur[tid] = lbase;                    // local cursor
        if (node < N) {
            ptr[node] = bbase + lbase;
            float d = 1.0f + lw[tid];   // self-loop weight 1
            dis[node] = (d > 0.0f) ? (1.0f / sqrtf(d)) : 0.0f;
        }
    }
    __syncthreads();
    for (int i = tid; i < m; i += 1024) {
        int2 pk = bp[i];
        int lcol = pk.x & 255;
        int pos = atomicAdd(&cur[lcol], 1);  // local position in bucket
        int2 rec;
        rec.x = (int)(((unsigned)pk.x) >> 8);
        rec.y = pk.y;                    // raw w (dis folded into features)
        lcsr[pos] = rec;
    }
    __syncthreads();
    for (int i = tid; i < m; i += 1024)      // coalesced write-out
        csr[bbase + i] = lcsr[i];
}

// x' = dis[node] * x[node]  into N x 16 fp16 rows (cols 10-15 zero)
__global__ void k_stage(const float* __restrict__ x, const float* __restrict__ dis,
                        __half* __restrict__ xp, int n) {
    int gid = blockIdx.x * blockDim.x + threadIdx.x;
    int node = gid >> 4, f = gid & 15;
    if (node < n)
        xp[(size_t)node * 16 + f] = __float2half((f < 10) ? dis[node] * x[(size_t)node * 10 + f] : 0.0f);
}

// y[c] = dis[c] * ( sum_e w_e * x'[row_e] + x'[c] )   (fp16 32B rows)
// 4 nodes per wave: quarter q owns node 4*wid+q, f = lane&15. Each
// quarter loads its own 16-record CSR chunk; shfl src (lane&48)|j.
// One gather instr = 4 distinct 32B segments. Output y fp32. (R22 body)
__global__ __launch_bounds__(256, 4)
void k_agg16(const __half* __restrict__ xp, const float* __restrict__ dis,
             const int* __restrict__ ptr, const int2* __restrict__ csr,
             float* __restrict__ y, int n) {
    int wid = (blockIdx.x * blockDim.x + threadIdx.x) >> 6;
    int lane = threadIdx.x & 63;
    int f = lane & 15;
    int laneq = lane & 48;
    int node = 4 * wid + (lane >> 4);
    bool valid = node < n;
    int s = 0, e = 0;
    if (valid) { s = ptr[node]; e = ptr[node + 1]; }
    int len = e - s;
    int m01 = max(__shfl(len, 0, 64), __shfl(len, 16, 64));
    int m23 = max(__shfl(len, 32, 64), __shfl(len, 48, 64));
    int maxlen = max(m01, m23);
    float a0 = 0.0f, a1 = 0.0f, a2 = 0.0f, a3 = 0.0f;
    for (int off = 0; off < maxlen; off += 16) {
        int idxv = 0; float nrmv = 0.0f;
        if (off + f < len) {
            int2 v = csr[s + off + f];
            idxv = v.x;
            nrmv = __int_as_float(v.y);
        }
        float wt[16], vt[16];
#pragma unroll
        for (int j = 0; j < 16; j++) {
            int r = __shfl(idxv, laneq | j, 64);
            wt[j] = __shfl(nrmv, laneq | j, 64);
            vt[j] = __half2float(xp[(size_t)r * 16 + f]);
        }
#pragma unroll
        for (int j = 0; j < 16; j += 4) {
            a0 = fmaf(wt[j],     vt[j],     a0);
            a1 = fmaf(wt[j + 1], vt[j + 1], a1);
            a2 = fmaf(wt[j + 2], vt[j + 2], a2);
            a3 = fmaf(wt[j + 3], vt[j + 3], a3);
        }
    }
    if (valid) {
        float acc = (a0 + a1) + (a2 + a3);
        float r = dis[node] * (acc + __half2float(xp[(size_t)node * 16 + f]));
        y[(size_t)node * 16 + f] = r;   // cols 10-15 compute to 0
    }
}

// hw2 = dis * ( relu(y @ W1 + b1) @ W2 )  -- 32 nodes/block (4 iters
// over LDS-staged weights: 4x fewer weight-staging reads). Output fp16
// rows (stride 32 halves = 64B).
__global__ __launch_bounds__(256)
void k_lin1(const float* __restrict__ y, const float* __restrict__ W1,
            const float* __restrict__ b1, const float* __restrict__ W2,
            const float* __restrict__ dis, __half* __restrict__ out, int n) {
    __shared__ float W1s[10 * 32];
    __shared__ float W2s[30 * 32];
    __shared__ float b1s[32];
    __shared__ float ys[8][16];
    __shared__ float hs[8][32];
    int tid = threadIdx.x;
    for (int i = tid; i < 10 * 32; i += 256) { int k = i >> 5, f = i & 31; W1s[i] = (f < 30) ? W1[k * 30 + f] : 0.0f; }
    for (int i = tid; i < 30 * 32; i += 256) { int k = i >> 5, f = i & 31; W2s[i] = (f < 30) ? W2[k * 30 + f] : 0.0f; }
    if (tid < 32) b1s[tid] = (tid < 30) ? b1[tid] : 0.0f;
    int n8 = tid >> 5, f = tid & 31;
    __syncthreads();
    for (int it = 0; it < 4; ++it) {
        int node = blockIdx.x * 32 + it * 8 + n8;
        if (node < n && f < 16) ys[n8][f] = y[(size_t)node * 16 + f];
        __syncthreads();                 // also guards hs reuse from prev iter
        if (node < n) {
            float h = b1s[f];
#pragma unroll
            for (int k = 0; k < 10; k++) h += ys[n8][k] * W1s[k * 32 + f];
            h = fmaxf(h, 0.0f);
            if (f >= 30) h = 0.0f;
            hs[n8][f] = h;
        }
        __syncthreads();
        if (node < n) {
            float o = 0.0f;
#pragma unroll
            for (int k = 0; k < 30; k++) o += hs[n8][k] * W2s[k * 32 + f];
            out[(size_t)node * 32 + f] = __float2half(o * dis[node]);  // cols>=30 are 0
        }
    }
}

// hw' = dis[node] * (in @ W)   (W is 30 x 30 row-major), in fp16 rows
// (h2 stored fp16), out fp16 rows stride 32 (cols 30,31 zeroed).
__global__ void k_matmul30(const __half* __restrict__ in,
                           const float* __restrict__ W, const float* __restrict__ dis,
                           __half* __restrict__ out, int n) {
    __shared__ float Ws[30 * 30];
    for (int idx = threadIdx.x; idx < 30 * 30; idx += blockDim.x) Ws[idx] = W[idx];
    __syncthreads();
    int gid = blockIdx.x * blockDim.x + threadIdx.x;
    int node = gid >> 5;
    int f = gid & 31;
    if (node < n) {
        float acc = 0.0f;
        if (f < 30) {
            const __half* ip = in + (size_t)node * 32;
#pragma unroll
            for (int k = 0; k < 30; k++) acc += __half2float(ip[k]) * Ws[k * 30 + f];
            acc *= dis[node];
        }
        out[(size_t)node * 32 + f] = __float2half(acc);   // coalesced, zero pad
    }
}

// h = relu( dis[c] * ( sum_e w_e*hw'[row_e] + hw'[c] ) + b )  -> fp16
// One wave per node; halves process even/odd edges -> 2 distinct 64B
// segments per gather instr (fp16 rows). R22 body, fp16 store epilogue.
__global__ __launch_bounds__(256, 4)
void k_agg_store(const __half* __restrict__ hw, const float* __restrict__ dis,
                 const int* __restrict__ ptr, const int2* __restrict__ csr,
                 const float* __restrict__ bias,
                 __half* __restrict__ out, int n) {
    int wid = (blockIdx.x * blockDim.x + threadIdx.x) >> 6;
    int lane = threadIdx.x & 63;
    if (wid >= n) return;
    int f = lane & 31;
    int half = lane >> 5;
    int s = ptr[wid];
    int e = ptr[wid + 1];
    float a0 = 0.0f, a1 = 0.0f, a2 = 0.0f, a3 = 0.0f;
    for (int base = s; base < e; base += 32) {
        int idxv = 0; float nrmv = 0.0f;
        int src = base + lane;
        if (lane < 32 && src < e) {
            int2 v = csr[src];
            idxv = v.x;
            nrmv = __int_as_float(v.y);
        }
        float wt[16], vt[16];
#pragma unroll
        for (int j = 0; j < 16; j++) {
            int sl = 2 * j + half;               // halves take even/odd edges
            int r = __shfl(idxv, sl, 64);
            wt[j] = __shfl(nrmv, sl, 64);
            vt[j] = __half2float(hw[(size_t)r * 32 + f]);
        }
#pragma unroll
        for (int j = 0; j < 16; j += 4) {
            a0 = fmaf(wt[j],     vt[j],     a0);
            a1 = fmaf(wt[j + 1], vt[j + 1], a1);
            a2 = fmaf(wt[j + 2], vt[j + 2], a2);
            a3 = fmaf(wt[j + 3], vt[j + 3], a3);
        }
    }
    float acc = (a0 + a1) + (a2 + a3);
    acc += __shfl_xor(acc, 32, 64);
    float dc = dis[wid];
    float r = dc * (acc + __half2float(hw[(size_t)wid * 32 + f]));
    if (half == 0) {
        float v = (f < 30) ? fmaxf(r + bias[f], 0.0f) : 0.0f;
        out[(size_t)wid * 32 + f] = __float2half(v);
    }
}

// Same loop, pool epilogue with LDS block pre-reduction (R22): one
// atomic set per block when the 4 consecutive nodes share a group.
__global__ __launch_bounds__(256, 4)
void k_agg_pool(const __half* __restrict__ hw, const float* __restrict__ dis,
                const int* __restrict__ ptr, const int2* __restrict__ csr,
                const float* __restrict__ bias, const int* __restrict__ batch,
                float* __restrict__ pooled, int n) {
    __shared__ float red[4][32];
    __shared__ int grp[4];
    int wid = (blockIdx.x * blockDim.x + threadIdx.x) >> 6;
    int lane = threadIdx.x & 63;
    int f = lane & 31;
    int half = lane >> 5;
    bool valid = wid < n;
    int s = 0, e = 0;
    if (valid) { s = ptr[wid]; e = ptr[wid + 1]; }
    float a0 = 0.0f, a1 = 0.0f, a2 = 0.0f, a3 = 0.0f;
    for (int base = s; base < e; base += 32) {
        int idxv = 0; float nrmv = 0.0f;
        int src = base + lane;
        if (lane < 32 && src < e) {
            int2 v = csr[src];
            idxv = v.x;
            nrmv = __int_as_float(v.y);
        }
        float wt[16], vt[16];
#pragma unroll
        for (int j = 0; j < 16; j++) {
            int sl = 2 * j + half;
            int r = __shfl(idxv, sl, 64);
            wt[j] = __shfl(nrmv, sl, 64);
            vt[j] = __half2float(hw[(size_t)r * 32 + f]);
        }
#pragma unroll
        for (int j = 0; j < 16; j += 4) {
            a0 = fmaf(wt[j],     vt[j],     a0);
            a1 = fmaf(wt[j + 1], vt[j + 1], a1);
            a2 = fmaf(wt[j + 2], vt[j + 2], a2);
            a3 = fmaf(wt[j + 3], vt[j + 3], a3);
        }
    }
    float acc = (a0 + a1) + (a2 + a3);
    acc += __shfl_xor(acc, 32, 64);
    float rv = 0.0f;
    if (valid && half == 0 && f < 30) {
        float dc = dis[wid];
        float r = dc * (acc + __half2float(hw[(size_t)wid * 32 + f]));
        rv = fmaxf(r + bias[f], 0.0f);
    }
    int w = threadIdx.x >> 6;                 // wave index in block (0..3)
    if (half == 0) red[w][f] = rv;            // f>=30 lanes write 0
    if (lane == 0) grp[w] = valid ? batch[wid] : -1;
    __syncthreads();
    if (w == 0 && half == 0 && f < 30) {
        int g0 = grp[0], g1 = grp[1], g2 = grp[2], g3 = grp[3];
        if (g0 >= 0 && g0 == g1 && g0 == g2 && g0 == g3) {
            float m = fmaxf(fmaxf(red[0][f], red[1][f]), fmaxf(red[2][f], red[3][f]));
            atomicMax((int*)&pooled[g0 * 32 + f], __float_as_int(m));
        } else {
            if (g0 >= 0) atomicMax((int*)&pooled[g0 * 32 + f], __float_as_int(red[0][f]));
            if (g1 >= 0) atomicMax((int*)&pooled[g1 * 32 + f], __float_as_int(red[1][f]));
            if (g2 >= 0) atomicMax((int*)&pooled[g2 * 32 + f], __float_as_int(red[2][f]));
            if (g3 >= 0) atomicMax((int*)&pooled[g3 * 32 + f], __float_as_int(red[3][f]));
        }
    }
}

__global__ void k_mlp(const float* __restrict__ pooled,
                      const float* __restrict__ LW1, const float* __restrict__ Lb1,
                      const float* __restrict__ LW2, const float* __restrict__ Lb2,
                      float* __restrict__ out, int G) {
    int g = blockIdx.x * blockDim.x + threadIdx.x;
    if (g >= G) return;
    float p[30];
#pragma unroll
    for (int k = 0; k < 30; k++) p[k] = pooled[g * 32 + k];
    float o0 = Lb2[0], o1 = Lb2[1];
#pragma unroll
    for (int j = 0; j < 10; j++) {
        float hj = Lb1[j];
#pragma unroll
        for (int k = 0; k < 30; k++) hj += p[k] * LW1[k * 10 + j];
        hj = fmaxf(hj, 0.0f);
        o0 += hj * LW2[j * 2 + 0];
        o1 += hj * LW2[j * 2 + 1];
    }
    out[g * 2 + 0] = o0;
    out[g * 2 + 1] = o1;
}

extern "C" void kernel_launch(void* const* d_in, const int* in_sizes, int n_in,
                              void* d_out, int out_size, void* d_ws, size_t ws_size,
                              hipStream_t stream) {
    const float* x     = (const float*)d_in[0];
    const int*   ei    = (const int*)d_in[1];
    const int*   batch = (const int*)d_in[2];
    const float* ew    = (const float*)d_in[3];
    const float* W1 = (const float*)d_in[4];  const float* b1  = (const float*)d_in[5];
    const float* W2 = (const float*)d_in[6];  const float* b2  = (const float*)d_in[7];
    const float* W3 = (const float*)d_in[8];  const float* b3  = (const float*)d_in[9];
    const float* LW1 = (const float*)d_in[10]; const float* Lb1 = (const float*)d_in[11];
    const float* LW2 = (const float*)d_in[12]; const float* Lb2 = (const float*)d_in[13];
    float* out = (float*)d_out;

    const int N = in_sizes[2];       // batch has N entries
    const int E = in_sizes[3];       // edge_weights has E entries
    const int G = out_size / 2;
    const int* row = ei;
    const int* col = ei + E;

    const int NB = (N + 255) >> 8;   // 391 buckets (must be <= 512)

    char* p = (char*)d_ws;
    auto carve = [&](size_t bytes) -> void* {
        void* r = (void*)p;
        p += (bytes + 255) & ~(size_t)255;
        return r;
    };
    int*   ptr       = (int*)carve((size_t)(N + 1) * 4);
    float* dis       = (float*)carve((size_t)N * 4);
    int*   bcur      = (int*)carve((size_t)NB * 16 * 4);
    int2*  csr       = (int2*)carve((size_t)E * 8);
    // regionA: bucket storage (build) aliased with feature buffers (layers).
    // Layer layout: [h2 fp16: N*32*2][...][bufB fp16: N*32*2 at N*32*4].
    // xp (fp16, N*16*2) at offset 0 and y16 (fp32, N*16*4) at offset
    // N*16*2 both alias h2's region; both dead before layer-2 writes.
    size_t buckBytes = (size_t)NB * CAP * 8;
    size_t featBytes = (size_t)N * 32 * 4 * 2;
    char*  regionA   = (char*)carve(buckBytes > featBytes ? buckBytes : featBytes);
    int2*  buck      = (int2*)regionA;
    __half* h2buf    = (__half*)regionA;                            // N*32 fp16
    __half* xp       = (__half*)regionA;                            // N*16 fp16
    float* y16       = (float*)(regionA + (size_t)N * 16 * 2);      // N*16 fp32
    __half* bufB     = (__half*)(regionA + (size_t)N * 32 * 4);     // N*32 fp16
    float* pooled    = (float*)carve((size_t)G * 32 * 4);

    int initN = (NB * 16 > G * 32) ? NB * 16 : G * 32;

    // --- build CSR ---
    k_init<<<(initN + WG - 1) / WG, WG, 0, stream>>>(bcur, pooled, NB * 16, G * 32);
    k_bucket<<<(E + T_EDGES - 1) / T_EDGES, 1024, 0, stream>>>(row, col, ew, bcur, buck, E, NB);
    k_fuse<<<NB, 1024, 0, stream>>>(bcur, buck, dis, ptr, csr, N, NB);

    int agg_grid   = (int)(((size_t)N * 64 + WG - 1) / WG);              // 1 node/wave
    int agg16_grid = (int)(((size_t)((N + 3) / 4) * 64 + WG - 1) / WG);  // 4 nodes/wave
    int mm_grid    = (int)(((size_t)N * 32 + WG - 1) / WG);

    // layer 1 in 10-dim space: y = dc*(sum w*x'_r + x'_c), then lin1
    k_stage<<<(int)(((size_t)N * 16 + WG - 1) / WG), WG, 0, stream>>>(x, dis, xp, N);
    k_agg16<<<agg16_grid, WG, 0, stream>>>(xp, dis, ptr, csr, y16, N);
    k_lin1<<<(N + 31) / 32, 256, 0, stream>>>(y16, W1, b1, W2, dis, bufB, N);  // bufB = hw2 (fp16)
    // layer 2
    k_agg_store<<<agg_grid, WG, 0, stream>>>(bufB, dis, ptr, csr, b2, h2buf, N); // h2 (fp16)
    k_matmul30<<<mm_grid, WG, 0, stream>>>(h2buf, W3, dis, bufB, N);          // bufB = hw3 (fp16)
    // layer 3 + fused segment-max pool (LDS pre-reduced atomics)
    k_agg_pool<<<agg_grid, WG, 0, stream>>>(bufB, dis, ptr, csr, b3, batch, pooled, N);

    // head
    k_mlp<<<(G + WG - 1) / WG, WG, 0, stream>>>(pooled, LW1, Lb1, LW2, Lb2, out, G);
}